// Round 7
// baseline (579.906 us; speedup 1.0000x reference)
//
#include <hip/hip_runtime.h>

#define N_NODES 50000
#define N_EDGES 800000
#define IN_DIM 512
#define NEG_SLOPE 0.2f

typedef short short8 __attribute__((ext_vector_type(8)));
typedef float f32x16 __attribute__((ext_vector_type(16)));

// ---------------- bf16 helpers ----------------
__device__ __forceinline__ unsigned bf16rne(float f) {
  union { float f; unsigned u; } v;
  v.f = f;
  return (v.u + 0x7FFFu + ((v.u >> 16) & 1u)) >> 16;
}
__device__ __forceinline__ float bf16tof(unsigned b) {
  union { unsigned u; float f; } v;
  v.u = b << 16;
  return v.f;
}
// truncation split: hi = trunc16(f); lo = trunc16(f - hi). err ~2^-14 rel.
__device__ __forceinline__ void tsplit8(float4 a, float4 b, short8& hi,
                                        short8& lo) {
  float fa[8] = {a.x, a.y, a.z, a.w, b.x, b.y, b.z, b.w};
#pragma unroll
  for (int i = 0; i < 8; i++) {
    unsigned u = __float_as_uint(fa[i]);
    hi[i] = (short)(u >> 16);
    float lof = fa[i] - __uint_as_float(u & 0xffff0000u);
    lo[i] = (short)(__float_as_uint(lof) >> 16);
  }
}

// ---------------- W pre-pack into MFMA B-fragment order ----------------
__global__ void pack_w(const float* __restrict__ W, short* __restrict__ Bhi,
                       short* __restrict__ Blo, int N) {
  int k = blockIdx.x, n = threadIdx.x;
  float w = W[(size_t)k * N + n];
  unsigned h = bf16rne(w);
  unsigned l = bf16rne(w - bf16tof(h));
  int ksub = k >> 4, kh = (k >> 3) & 1, j = k & 7;
  int nsub = n >> 5, lane2 = (n & 31) | (kh << 5);
  size_t off = (((size_t)ksub * (N >> 5) + nsub) * 64 + lane2) * 8 + j;
  Bhi[off] = (short)h;
  Blo[off] = (short)l;
}

// ---------------- split-bf16 MFMA GEMM v3 ----------------
// 32x64 wave tile; group-of-2 K-steps; batched loads + register double-buffer;
// bf16 output only. 3-term split: hh + hl + lh.
template <int K, int NSUBS, int NTILES>
__global__ __launch_bounds__(256) void gemm_mfma(
    const float* __restrict__ A, const short* __restrict__ Bhi_,
    const short* __restrict__ Blo_, unsigned short* __restrict__ Cb, int M) {
  const int N = NSUBS * 32;
  constexpr int U = 2;
  constexpr int G = K / 16 / U;
  int lane = threadIdx.x & 63;
  int wid = blockIdx.x * 4 + (threadIdx.x >> 6);
  int mtiles = (M + 31) >> 5;
  int mtile = wid / NTILES, ntile = wid % NTILES;
  if (mtile >= mtiles) return;
  int half = lane >> 5, l31 = lane & 31;
  int m0 = mtile * 32;
  int r0 = min(m0 + l31, M - 1);
  const float* ap = A + (size_t)r0 * K + half * 8;
  const short8* bh = (const short8*)Bhi_;
  const short8* bl = (const short8*)Blo_;
  size_t bidx = (size_t)(ntile * 2) * 64 + lane;
  f32x16 acc0 = {}, acc1 = {};
  float4 cx[U][2];
  short8 cbh[U][2], cbl[U][2];
#pragma unroll
  for (int u = 0; u < U; u++) {
    cx[u][0] = *(const float4*)(ap + u * 16);
    cx[u][1] = *(const float4*)(ap + u * 16 + 4);
    size_t bb = bidx + (size_t)u * NSUBS * 64;
    cbh[u][0] = bh[bb];
    cbl[u][0] = bl[bb];
    cbh[u][1] = bh[bb + 64];
    cbl[u][1] = bl[bb + 64];
  }
  for (int g = 0; g < G; g++) {
    int gn = (g + 1 < G) ? g + 1 : g;
    float4 nx[U][2];
    short8 nbh[U][2], nbl[U][2];
#pragma unroll
    for (int u = 0; u < U; u++) {
      int ks = gn * U + u;
      nx[u][0] = *(const float4*)(ap + ks * 16);
      nx[u][1] = *(const float4*)(ap + ks * 16 + 4);
      size_t bb = bidx + (size_t)ks * NSUBS * 64;
      nbh[u][0] = bh[bb];
      nbl[u][0] = bl[bb];
      nbh[u][1] = bh[bb + 64];
      nbl[u][1] = bl[bb + 64];
    }
#pragma unroll
    for (int u = 0; u < U; u++) {
      short8 ah, al8;
      tsplit8(cx[u][0], cx[u][1], ah, al8);
      acc0 = __builtin_amdgcn_mfma_f32_32x32x16_bf16(ah, cbh[u][0], acc0, 0, 0, 0);
      acc0 = __builtin_amdgcn_mfma_f32_32x32x16_bf16(ah, cbl[u][0], acc0, 0, 0, 0);
      acc0 = __builtin_amdgcn_mfma_f32_32x32x16_bf16(al8, cbh[u][0], acc0, 0, 0, 0);
      acc1 = __builtin_amdgcn_mfma_f32_32x32x16_bf16(ah, cbh[u][1], acc1, 0, 0, 0);
      acc1 = __builtin_amdgcn_mfma_f32_32x32x16_bf16(ah, cbl[u][1], acc1, 0, 0, 0);
      acc1 = __builtin_amdgcn_mfma_f32_32x32x16_bf16(al8, cbh[u][1], acc1, 0, 0, 0);
    }
#pragma unroll
    for (int u = 0; u < U; u++) {
      cx[u][0] = nx[u][0];
      cx[u][1] = nx[u][1];
      cbh[u][0] = nbh[u][0];
      cbl[u][0] = nbl[u][0];
      cbh[u][1] = nbh[u][1];
      cbl[u][1] = nbl[u][1];
    }
  }
  // C/D layout (m74/m101): col=lane&31, row=(r&3)+8*(r>>2)+4*half
  int colbase = ntile * 64 + l31;
#pragma unroll
  for (int r = 0; r < 16; r++) {
    int roff = (r & 3) + 8 * (r >> 2) + 4 * half;
    int row = m0 + roff;
    if (row < M) {
      Cb[(size_t)row * N + colbase] = (unsigned short)bf16rne(acc0[r]);
      Cb[(size_t)row * N + colbase + 32] = (unsigned short)bf16rne(acc1[r]);
    }
  }
}

// ---------------- el/er reductions (bf16 input) ----------------
__global__ __launch_bounds__(256) void elr1_kernel(
    const unsigned short* __restrict__ fb, const float* __restrict__ al,
    const float* __restrict__ ar, float* __restrict__ el,
    float* __restrict__ er) {
  int n = blockIdx.x;
  int t = threadIdx.x;
  int h = t >> 6, lane = t & 63;
  float v = bf16tof(fb[(size_t)n * 256 + t]);
  float a = v * al[t];
  float b = v * ar[t];
  for (int off = 32; off; off >>= 1) {
    a += __shfl_down(a, off);
    b += __shfl_down(b, off);
  }
  if (lane == 0) {
    el[n * 4 + h] = a;
    er[n * 4 + h] = b;
  }
}

__global__ __launch_bounds__(256) void elr2_kernel(
    const unsigned short* __restrict__ fb2, const float* __restrict__ al,
    const float* __restrict__ ar, float* __restrict__ el,
    float* __restrict__ er) {
  int w = threadIdx.x >> 6, lane = threadIdx.x & 63;
  int n = blockIdx.x * 4 + w;
  if (n >= N_NODES) return;
  float v = bf16tof(fb2[(size_t)n * 64 + lane]);
  float a = v * al[lane], b = v * ar[lane];
  for (int off = 32; off; off >>= 1) {
    a += __shfl_down(a, off);
    b += __shfl_down(b, off);
  }
  if (lane == 0) {
    el[n] = a;
    er[n] = b;
  }
}

// ---------------- CSR build ----------------
__global__ void hist_kernel(const int* __restrict__ dst,
                            int* __restrict__ counts) {
  int e = blockIdx.x * blockDim.x + threadIdx.x;
  if (e < N_EDGES) atomicAdd(&counts[dst[e]], 1);
}

#define NSCAN 196  // ceil(50000/256)
__global__ __launch_bounds__(256) void scan_part(const int* __restrict__ counts,
                                                 int* __restrict__ offsets,
                                                 int* __restrict__ bsums) {
  __shared__ int sh[256];
  int t = threadIdx.x;
  int i = blockIdx.x * 256 + t;
  int v = (i < N_NODES) ? counts[i] : 0;
  sh[t] = v;
  __syncthreads();
  for (int o = 1; o < 256; o <<= 1) {
    int x = (t >= o) ? sh[t - o] : 0;
    __syncthreads();
    sh[t] += x;
    __syncthreads();
  }
  if (i < N_NODES) offsets[i] = sh[t] - v;
  if (t == 255) bsums[blockIdx.x] = sh[255];
}
__global__ __launch_bounds__(256) void scan_top(int* __restrict__ bsums) {
  __shared__ int sh[256];
  int t = threadIdx.x;
  int v = (t < NSCAN) ? bsums[t] : 0;
  sh[t] = v;
  __syncthreads();
  for (int o = 1; o < 256; o <<= 1) {
    int x = (t >= o) ? sh[t - o] : 0;
    __syncthreads();
    sh[t] += x;
    __syncthreads();
  }
  if (t < NSCAN) bsums[t] = sh[t] - v;
}
__global__ __launch_bounds__(256) void scan_add(int* __restrict__ offsets,
                                                const int* __restrict__ bsums) {
  int i = blockIdx.x * 256 + threadIdx.x;
  if (i < N_NODES) offsets[i] += bsums[blockIdx.x];
  if (i == 0) offsets[N_NODES] = N_EDGES;
}

__global__ void scatter_kernel(const int* __restrict__ src,
                               const int* __restrict__ dst,
                               const int* __restrict__ offsets,
                               int* __restrict__ fill,
                               int* __restrict__ csr_src) {
  int e = blockIdx.x * blockDim.x + threadIdx.x;
  if (e < N_EDGES) {
    int d = dst[e];
    int pos = offsets[d] + atomicAdd(&fill[d], 1);
    csr_src[pos] = src[e];
  }
}

// ---------------- fused softmax-stats + aggregation, layer 1 ----------------
// block = node. Pass 1: 256 threads stride edges, online (m,l) per head,
// butterfly + LDS combine. Pass 2: wave-strided weighted bf16 gather.
__global__ __launch_bounds__(256) void agg1_kernel(
    const int* __restrict__ offsets, const int* __restrict__ csr_src,
    const float* __restrict__ el, const float* __restrict__ er,
    const unsigned short* __restrict__ fb, const float* __restrict__ bias,
    float* __restrict__ h1) {
  __shared__ float red[3][256];
  __shared__ float sm[4][4], sl[4][4];
  int n = blockIdx.x;
  int t = threadIdx.x;
  int w = t >> 6, lane = t & 63;
  int off0 = offsets[n], deg = offsets[n + 1] - off0;
  float4 erv = ((const float4*)er)[n];
  float er4[4] = {erv.x, erv.y, erv.z, erv.w};
  // pass 1: online softmax stats
  float m[4] = {-1e30f, -1e30f, -1e30f, -1e30f};
  float l[4] = {0.f, 0.f, 0.f, 0.f};
  for (int i = t; i < deg; i += 256) {
    int s = csr_src[off0 + i];
    float4 elv = ((const float4*)el)[s];
    float e4[4] = {elv.x, elv.y, elv.z, elv.w};
#pragma unroll
    for (int h = 0; h < 4; h++) {
      float v = e4[h] + er4[h];
      v = v > 0.f ? v : NEG_SLOPE * v;
      float nm = fmaxf(m[h], v);
      l[h] = l[h] * __expf(m[h] - nm) + __expf(v - nm);
      m[h] = nm;
    }
  }
#pragma unroll
  for (int d = 32; d; d >>= 1) {
#pragma unroll
    for (int h = 0; h < 4; h++) {
      float mo = __shfl_xor(m[h], d);
      float lo = __shfl_xor(l[h], d);
      float nm = fmaxf(m[h], mo);
      l[h] = l[h] * __expf(m[h] - nm) + lo * __expf(mo - nm);
      m[h] = nm;
    }
  }
  if (lane == 0) {
#pragma unroll
    for (int h = 0; h < 4; h++) {
      sm[w][h] = m[h];
      sl[w][h] = l[h];
    }
  }
  __syncthreads();
  int hh = lane >> 4;
  float M4 = fmaxf(fmaxf(sm[0][hh], sm[1][hh]), fmaxf(sm[2][hh], sm[3][hh]));
  float L4 = sl[0][hh] * __expf(sm[0][hh] - M4) +
             sl[1][hh] * __expf(sm[1][hh] - M4) +
             sl[2][hh] * __expf(sm[2][hh] - M4) +
             sl[3][hh] * __expf(sm[3][hh] - M4);
  float erh = er4[hh];
  float invd = 1.0f / L4;  // deg==0: inf, never multiplied
  // pass 2: weighted aggregate (bf16 payload)
  float4 acc = {0.f, 0.f, 0.f, 0.f};
  float4 acc2 = {0.f, 0.f, 0.f, 0.f};
  int i = w;
  for (; i + 4 < deg; i += 8) {
    int s0 = csr_src[off0 + i];
    int s1 = csr_src[off0 + i + 4];
    float e0 = el[s0 * 4 + hh] + erh;
    float e1 = el[s1 * 4 + hh] + erh;
    e0 = e0 > 0.f ? e0 : NEG_SLOPE * e0;
    e1 = e1 > 0.f ? e1 : NEG_SLOPE * e1;
    float a0 = __expf(e0 - M4) * invd;
    float a1 = __expf(e1 - M4) * invd;
    uint2 p0 = *(const uint2*)(fb + (size_t)s0 * 256 + lane * 4);
    uint2 p1 = *(const uint2*)(fb + (size_t)s1 * 256 + lane * 4);
    acc.x += a0 * __uint_as_float(p0.x << 16);
    acc.y += a0 * __uint_as_float(p0.x & 0xffff0000u);
    acc.z += a0 * __uint_as_float(p0.y << 16);
    acc.w += a0 * __uint_as_float(p0.y & 0xffff0000u);
    acc2.x += a1 * __uint_as_float(p1.x << 16);
    acc2.y += a1 * __uint_as_float(p1.x & 0xffff0000u);
    acc2.z += a1 * __uint_as_float(p1.y << 16);
    acc2.w += a1 * __uint_as_float(p1.y & 0xffff0000u);
  }
  if (i < deg) {
    int s0 = csr_src[off0 + i];
    float e0 = el[s0 * 4 + hh] + erh;
    e0 = e0 > 0.f ? e0 : NEG_SLOPE * e0;
    float a0 = __expf(e0 - M4) * invd;
    uint2 p0 = *(const uint2*)(fb + (size_t)s0 * 256 + lane * 4);
    acc.x += a0 * __uint_as_float(p0.x << 16);
    acc.y += a0 * __uint_as_float(p0.x & 0xffff0000u);
    acc.z += a0 * __uint_as_float(p0.y << 16);
    acc.w += a0 * __uint_as_float(p0.y & 0xffff0000u);
  }
  acc.x += acc2.x;
  acc.y += acc2.y;
  acc.z += acc2.z;
  acc.w += acc2.w;
  if (w) *(float4*)(&red[w - 1][lane * 4]) = acc;
  __syncthreads();
  if (w == 0) {
    float4 r0 = *(float4*)(&red[0][lane * 4]);
    float4 r1 = *(float4*)(&red[1][lane * 4]);
    float4 r2 = *(float4*)(&red[2][lane * 4]);
    float4 b = ((const float4*)bias)[lane];
    float o[4] = {acc.x + r0.x + r1.x + r2.x + b.x,
                  acc.y + r0.y + r1.y + r2.y + b.y,
                  acc.z + r0.z + r1.z + r2.z + b.z,
                  acc.w + r0.w + r1.w + r2.w + b.w};
#pragma unroll
    for (int j = 0; j < 4; j++) o[j] = o[j] > 0.f ? o[j] : __expf(o[j]) - 1.0f;
    float4 ov = {o[0], o[1], o[2], o[3]};
    *(float4*)(h1 + (size_t)n * 256 + lane * 4) = ov;
  }
}

// ---------------- fused softmax-stats + aggregation, layer 2 ----------------
// wave = node (4/block). Pass 1: lanes stride edges, butterfly (m,l).
// Pass 2: eslot-strided bf16 gather, xor-combine.
__global__ __launch_bounds__(256) void agg2_kernel(
    const int* __restrict__ offsets, const int* __restrict__ csr_src,
    const float* __restrict__ el, const float* __restrict__ er,
    const unsigned short* __restrict__ fb2, const float* __restrict__ bias,
    float* __restrict__ out) {
  int w = threadIdx.x >> 6, lane = threadIdx.x & 63;
  int n = blockIdx.x * 4 + w;
  if (n >= N_NODES) return;
  int off0 = offsets[n], deg = offsets[n + 1] - off0;
  float ern = er[n];
  float m = -1e30f, l = 0.f;
  for (int i = lane; i < deg; i += 64) {
    int s = csr_src[off0 + i];
    float v = el[s] + ern;
    v = v > 0.f ? v : NEG_SLOPE * v;
    float nm = fmaxf(m, v);
    l = l * __expf(m - nm) + __expf(v - nm);
    m = nm;
  }
#pragma unroll
  for (int d = 32; d; d >>= 1) {
    float mo = __shfl_xor(m, d);
    float lo = __shfl_xor(l, d);
    float nm = fmaxf(m, mo);
    l = l * __expf(m - nm) + lo * __expf(mo - nm);
    m = nm;
  }
  float invd = 1.0f / l;
  int dg = lane & 15, eslot = lane >> 4;
  float4 acc = {0.f, 0.f, 0.f, 0.f};
  for (int i = eslot; i < deg; i += 4) {
    int s = csr_src[off0 + i];
    float e = el[s] + ern;
    e = e > 0.f ? e : NEG_SLOPE * e;
    float a = __expf(e - m) * invd;
    uint2 p = *(const uint2*)(fb2 + (size_t)s * 64 + dg * 4);
    acc.x += a * __uint_as_float(p.x << 16);
    acc.y += a * __uint_as_float(p.x & 0xffff0000u);
    acc.z += a * __uint_as_float(p.y << 16);
    acc.w += a * __uint_as_float(p.y & 0xffff0000u);
  }
#pragma unroll
  for (int off = 16; off < 64; off <<= 1) {
    acc.x += __shfl_xor(acc.x, off);
    acc.y += __shfl_xor(acc.y, off);
    acc.z += __shfl_xor(acc.z, off);
    acc.w += __shfl_xor(acc.w, off);
  }
  if (eslot == 0) {
    float4 b = ((const float4*)bias)[dg];
    float4 ov = {acc.x + b.x, acc.y + b.y, acc.z + b.z, acc.w + b.w};
    *(float4*)(out + (size_t)n * 64 + dg * 4) = ov;
  }
}

extern "C" void kernel_launch(void* const* d_in, const int* in_sizes, int n_in,
                              void* d_out, int out_size, void* d_ws,
                              size_t ws_size, hipStream_t stream) {
  const float* features = (const float*)d_in[0];
  const float* W1 = (const float*)d_in[1];
  const float* al1 = (const float*)d_in[2];
  const float* ar1 = (const float*)d_in[3];
  const float* b1 = (const float*)d_in[4];
  const float* W2 = (const float*)d_in[5];
  const float* al2 = (const float*)d_in[6];
  const float* ar2 = (const float*)d_in[7];
  const float* b2 = (const float*)d_in[8];
  const int* src = (const int*)d_in[9];
  const int* dst = (const int*)d_in[10];
  float* out = (float*)d_out;

  // Workspace (~83 MB):
  //  h1 fp32 [N,256] (agg1 out -> gemm2 A)
  //  fb bf16 [N,256] (gemm1 out) -> dead after agg1 -> fb2 bf16 [N,64] reuses
  float* h1 = (float*)d_ws;                                   // 51.2 MB
  unsigned short* fb = (unsigned short*)(h1 + (size_t)N_NODES * 256);  // 25.6
  unsigned short* fb2 = fb;                                   // reuse (6.4)
  float* el1 = (float*)(fb + (size_t)N_NODES * 256);
  float* er1 = el1 + N_NODES * 4;
  float* el2 = er1 + N_NODES * 4;
  float* er2 = el2 + N_NODES;
  int* counts = (int*)(er2 + N_NODES);
  int* offsets = counts + N_NODES;
  int* fill = offsets + N_NODES + 1;
  int* csr_src = fill + N_NODES;
  int* bsums = csr_src + N_EDGES;

  // W packs: b1 in d_out (dead until agg2); b2 in `fill` (dead after scatter)
  short* b1hi = (short*)d_out;
  short* b1lo = b1hi + 512 * 256;
  short* b2hi = (short*)fill;
  short* b2lo = b2hi + 256 * 64;

  // --- CSR build ---
  hipMemsetAsync(counts, 0, N_NODES * sizeof(int), stream);
  hipMemsetAsync(fill, 0, N_NODES * sizeof(int), stream);
  hist_kernel<<<(N_EDGES + 255) / 256, 256, 0, stream>>>(dst, counts);
  scan_part<<<NSCAN, 256, 0, stream>>>(counts, offsets, bsums);
  scan_top<<<1, 256, 0, stream>>>(bsums);
  scan_add<<<NSCAN, 256, 0, stream>>>(offsets, bsums);
  scatter_kernel<<<(N_EDGES + 255) / 256, 256, 0, stream>>>(src, dst, offsets,
                                                            fill, csr_src);

  // --- weight packing ---
  pack_w<<<512, 256, 0, stream>>>(W1, b1hi, b1lo, 256);
  pack_w<<<256, 64, 0, stream>>>(W2, b2hi, b2lo, 64);

  // --- layer 1 ---
  gemm_mfma<IN_DIM, 8, 4><<<1563, 256, 0, stream>>>(features, b1hi, b1lo, fb,
                                                    N_NODES);
  elr1_kernel<<<N_NODES, 256, 0, stream>>>(fb, al1, ar1, el1, er1);
  agg1_kernel<<<N_NODES, 256, 0, stream>>>(offsets, csr_src, el1, er1, fb, b1,
                                           h1);

  // --- layer 2 ---
  gemm_mfma<256, 2, 1><<<391, 256, 0, stream>>>(h1, b2hi, b2lo, fb2, N_NODES);
  elr2_kernel<<<(N_NODES + 3) / 4, 256, 0, stream>>>(fb2, al2, ar2, el2, er2);
  agg2_kernel<<<(N_NODES + 3) / 4, 256, 0, stream>>>(offsets, csr_src, el2, er2,
                                                     fb2, b2, out);
}

// Round 8
// 543.114 us; speedup vs baseline: 1.0677x; 1.0677x over previous
//
#include <hip/hip_runtime.h>

#define N_NODES 50000
#define N_EDGES 800000
#define IN_DIM 512
#define NEG_SLOPE 0.2f

typedef short short8 __attribute__((ext_vector_type(8)));
typedef float f32x16 __attribute__((ext_vector_type(16)));

// ---------------- bf16 helpers ----------------
__device__ __forceinline__ unsigned bf16rne(float f) {
  union { float f; unsigned u; } v;
  v.f = f;
  return (v.u + 0x7FFFu + ((v.u >> 16) & 1u)) >> 16;
}
__device__ __forceinline__ float bf16tof(unsigned b) {
  union { unsigned u; float f; } v;
  v.u = b << 16;
  return v.f;
}
// truncation split: hi = trunc16(f); lo = trunc16(f - hi). err ~2^-14 rel.
__device__ __forceinline__ void tsplit8(float4 a, float4 b, short8& hi,
                                        short8& lo) {
  float fa[8] = {a.x, a.y, a.z, a.w, b.x, b.y, b.z, b.w};
#pragma unroll
  for (int i = 0; i < 8; i++) {
    unsigned u = __float_as_uint(fa[i]);
    hi[i] = (short)(u >> 16);
    float lof = fa[i] - __uint_as_float(u & 0xffff0000u);
    lo[i] = (short)(__float_as_uint(lof) >> 16);
  }
}

// ---------------- W pre-pack into MFMA B-fragment order ----------------
__global__ void pack_w(const float* __restrict__ W, short* __restrict__ Bhi,
                       short* __restrict__ Blo, int N) {
  int k = blockIdx.x, n = threadIdx.x;
  float w = W[(size_t)k * N + n];
  unsigned h = bf16rne(w);
  unsigned l = bf16rne(w - bf16tof(h));
  int ksub = k >> 4, kh = (k >> 3) & 1, j = k & 7;
  int nsub = n >> 5, lane2 = (n & 31) | (kh << 5);
  size_t off = (((size_t)ksub * (N >> 5) + nsub) * 64 + lane2) * 8 + j;
  Bhi[off] = (short)h;
  Blo[off] = (short)l;
}

// ---------------- split-bf16 MFMA GEMM v3 ----------------
// 32x64 wave tile; group-of-2 K-steps; batched loads + register double-buffer;
// bf16 output only. 3-term split: hh + hl + lh.
template <int K, int NSUBS, int NTILES>
__global__ __launch_bounds__(256) void gemm_mfma(
    const float* __restrict__ A, const short* __restrict__ Bhi_,
    const short* __restrict__ Blo_, unsigned short* __restrict__ Cb, int M) {
  const int N = NSUBS * 32;
  constexpr int U = 2;
  constexpr int G = K / 16 / U;
  int lane = threadIdx.x & 63;
  int wid = blockIdx.x * 4 + (threadIdx.x >> 6);
  int mtiles = (M + 31) >> 5;
  int mtile = wid / NTILES, ntile = wid % NTILES;
  if (mtile >= mtiles) return;
  int half = lane >> 5, l31 = lane & 31;
  int m0 = mtile * 32;
  int r0 = min(m0 + l31, M - 1);
  const float* ap = A + (size_t)r0 * K + half * 8;
  const short8* bh = (const short8*)Bhi_;
  const short8* bl = (const short8*)Blo_;
  size_t bidx = (size_t)(ntile * 2) * 64 + lane;
  f32x16 acc0 = {}, acc1 = {};
  float4 cx[U][2];
  short8 cbh[U][2], cbl[U][2];
#pragma unroll
  for (int u = 0; u < U; u++) {
    cx[u][0] = *(const float4*)(ap + u * 16);
    cx[u][1] = *(const float4*)(ap + u * 16 + 4);
    size_t bb = bidx + (size_t)u * NSUBS * 64;
    cbh[u][0] = bh[bb];
    cbl[u][0] = bl[bb];
    cbh[u][1] = bh[bb + 64];
    cbl[u][1] = bl[bb + 64];
  }
  for (int g = 0; g < G; g++) {
    int gn = (g + 1 < G) ? g + 1 : g;
    float4 nx[U][2];
    short8 nbh[U][2], nbl[U][2];
#pragma unroll
    for (int u = 0; u < U; u++) {
      int ks = gn * U + u;
      nx[u][0] = *(const float4*)(ap + ks * 16);
      nx[u][1] = *(const float4*)(ap + ks * 16 + 4);
      size_t bb = bidx + (size_t)ks * NSUBS * 64;
      nbh[u][0] = bh[bb];
      nbl[u][0] = bl[bb];
      nbh[u][1] = bh[bb + 64];
      nbl[u][1] = bl[bb + 64];
    }
#pragma unroll
    for (int u = 0; u < U; u++) {
      short8 ah, al8;
      tsplit8(cx[u][0], cx[u][1], ah, al8);
      acc0 = __builtin_amdgcn_mfma_f32_32x32x16_bf16(ah, cbh[u][0], acc0, 0, 0, 0);
      acc0 = __builtin_amdgcn_mfma_f32_32x32x16_bf16(ah, cbl[u][0], acc0, 0, 0, 0);
      acc0 = __builtin_amdgcn_mfma_f32_32x32x16_bf16(al8, cbh[u][0], acc0, 0, 0, 0);
      acc1 = __builtin_amdgcn_mfma_f32_32x32x16_bf16(ah, cbh[u][1], acc1, 0, 0, 0);
      acc1 = __builtin_amdgcn_mfma_f32_32x32x16_bf16(ah, cbl[u][1], acc1, 0, 0, 0);
      acc1 = __builtin_amdgcn_mfma_f32_32x32x16_bf16(al8, cbh[u][1], acc1, 0, 0, 0);
    }
#pragma unroll
    for (int u = 0; u < U; u++) {
      cx[u][0] = nx[u][0];
      cx[u][1] = nx[u][1];
      cbh[u][0] = nbh[u][0];
      cbl[u][0] = nbl[u][0];
      cbh[u][1] = nbh[u][1];
      cbl[u][1] = nbl[u][1];
    }
  }
  // C/D layout (m74/m101): col=lane&31, row=(r&3)+8*(r>>2)+4*half
  int colbase = ntile * 64 + l31;
#pragma unroll
  for (int r = 0; r < 16; r++) {
    int roff = (r & 3) + 8 * (r >> 2) + 4 * half;
    int row = m0 + roff;
    if (row < M) {
      Cb[(size_t)row * N + colbase] = (unsigned short)bf16rne(acc0[r]);
      Cb[(size_t)row * N + colbase + 32] = (unsigned short)bf16rne(acc1[r]);
    }
  }
}

// ---------------- el/er reductions (bf16 input) ----------------
__global__ __launch_bounds__(256) void elr1_kernel(
    const unsigned short* __restrict__ fb, const float* __restrict__ al,
    const float* __restrict__ ar, float* __restrict__ el,
    float* __restrict__ er) {
  int n = blockIdx.x;
  int t = threadIdx.x;
  int h = t >> 6, lane = t & 63;
  float v = bf16tof(fb[(size_t)n * 256 + t]);
  float a = v * al[t];
  float b = v * ar[t];
  for (int off = 32; off; off >>= 1) {
    a += __shfl_down(a, off);
    b += __shfl_down(b, off);
  }
  if (lane == 0) {
    el[n * 4 + h] = a;
    er[n * 4 + h] = b;
  }
}

__global__ __launch_bounds__(256) void elr2_kernel(
    const unsigned short* __restrict__ fb2, const float* __restrict__ al,
    const float* __restrict__ ar, float* __restrict__ el,
    float* __restrict__ er) {
  int w = threadIdx.x >> 6, lane = threadIdx.x & 63;
  int n = blockIdx.x * 4 + w;
  if (n >= N_NODES) return;
  float v = bf16tof(fb2[(size_t)n * 64 + lane]);
  float a = v * al[lane], b = v * ar[lane];
  for (int off = 32; off; off >>= 1) {
    a += __shfl_down(a, off);
    b += __shfl_down(b, off);
  }
  if (lane == 0) {
    el[n] = a;
    er[n] = b;
  }
}

// ---------------- CSR build ----------------
__global__ void hist_kernel(const int* __restrict__ dst,
                            int* __restrict__ counts) {
  int e = blockIdx.x * blockDim.x + threadIdx.x;
  if (e < N_EDGES) atomicAdd(&counts[dst[e]], 1);
}

#define NSCAN 196  // ceil(50000/256)
__global__ __launch_bounds__(256) void scan_part(const int* __restrict__ counts,
                                                 int* __restrict__ offsets,
                                                 int* __restrict__ bsums) {
  __shared__ int sh[256];
  int t = threadIdx.x;
  int i = blockIdx.x * 256 + t;
  int v = (i < N_NODES) ? counts[i] : 0;
  sh[t] = v;
  __syncthreads();
  for (int o = 1; o < 256; o <<= 1) {
    int x = (t >= o) ? sh[t - o] : 0;
    __syncthreads();
    sh[t] += x;
    __syncthreads();
  }
  if (i < N_NODES) offsets[i] = sh[t] - v;
  if (t == 255) bsums[blockIdx.x] = sh[255];
}
__global__ __launch_bounds__(256) void scan_top(int* __restrict__ bsums) {
  __shared__ int sh[256];
  int t = threadIdx.x;
  int v = (t < NSCAN) ? bsums[t] : 0;
  sh[t] = v;
  __syncthreads();
  for (int o = 1; o < 256; o <<= 1) {
    int x = (t >= o) ? sh[t - o] : 0;
    __syncthreads();
    sh[t] += x;
    __syncthreads();
  }
  if (t < NSCAN) bsums[t] = sh[t] - v;
}
__global__ __launch_bounds__(256) void scan_add(int* __restrict__ offsets,
                                                const int* __restrict__ bsums) {
  int i = blockIdx.x * 256 + threadIdx.x;
  if (i < N_NODES) offsets[i] += bsums[blockIdx.x];
  if (i == 0) offsets[N_NODES] = N_EDGES;
}

__global__ void scatter_kernel(const int* __restrict__ src,
                               const int* __restrict__ dst,
                               const int* __restrict__ offsets,
                               int* __restrict__ fill,
                               int* __restrict__ csr_src) {
  int e = blockIdx.x * blockDim.x + threadIdx.x;
  if (e < N_EDGES) {
    int d = dst[e];
    int pos = offsets[d] + atomicAdd(&fill[d], 1);
    csr_src[pos] = src[e];
  }
}

// ---------------- softmax max/denominator (online), separate ----------------
__global__ __launch_bounds__(256) void mden1_kernel(
    const int* __restrict__ offsets, const int* __restrict__ csr_src,
    const float* __restrict__ el, const float* __restrict__ er,
    float* __restrict__ mout, float* __restrict__ dout) {
  int w = threadIdx.x >> 6, lane = threadIdx.x & 63;
  int n = blockIdx.x * 4 + w;
  if (n >= N_NODES) return;
  int off0 = offsets[n], deg = offsets[n + 1] - off0;
  float4 erv = ((const float4*)er)[n];
  float er4[4] = {erv.x, erv.y, erv.z, erv.w};
  float m[4] = {-1e30f, -1e30f, -1e30f, -1e30f};
  float l[4] = {0.f, 0.f, 0.f, 0.f};
  for (int i = lane; i < deg; i += 64) {
    int s = csr_src[off0 + i];
    float4 elv = ((const float4*)el)[s];
    float e4[4] = {elv.x, elv.y, elv.z, elv.w};
#pragma unroll
    for (int h = 0; h < 4; h++) {
      float v = e4[h] + er4[h];
      v = v > 0.f ? v : NEG_SLOPE * v;
      float nm = fmaxf(m[h], v);
      l[h] = l[h] * __expf(m[h] - nm) + __expf(v - nm);
      m[h] = nm;
    }
  }
  for (int d = 32; d; d >>= 1) {
#pragma unroll
    for (int h = 0; h < 4; h++) {
      float mo = __shfl_down(m[h], d);
      float lo = __shfl_down(l[h], d);
      float nm = fmaxf(m[h], mo);
      l[h] = l[h] * __expf(m[h] - nm) + lo * __expf(mo - nm);
      m[h] = nm;
    }
  }
  if (lane == 0) {
#pragma unroll
    for (int h = 0; h < 4; h++) {
      mout[n * 4 + h] = m[h];
      dout[n * 4 + h] = l[h];
    }
  }
}

__global__ __launch_bounds__(256) void mden2_kernel(
    const int* __restrict__ offsets, const int* __restrict__ csr_src,
    const float* __restrict__ el, const float* __restrict__ er,
    float* __restrict__ mout, float* __restrict__ dout) {
  int w = threadIdx.x >> 6, lane = threadIdx.x & 63;
  int n = blockIdx.x * 4 + w;
  if (n >= N_NODES) return;
  int off0 = offsets[n], deg = offsets[n + 1] - off0;
  float ern = er[n];
  float m = -1e30f, l = 0.f;
  for (int i = lane; i < deg; i += 64) {
    int s = csr_src[off0 + i];
    float v = el[s] + ern;
    v = v > 0.f ? v : NEG_SLOPE * v;
    float nm = fmaxf(m, v);
    l = l * __expf(m - nm) + __expf(v - nm);
    m = nm;
  }
  for (int d = 32; d; d >>= 1) {
    float mo = __shfl_down(m, d);
    float lo = __shfl_down(l, d);
    float nm = fmaxf(m, mo);
    l = l * __expf(m - nm) + lo * __expf(mo - nm);
    m = nm;
  }
  if (lane == 0) {
    mout[n] = m;
    dout[n] = l;
  }
}

// ---------------- aggregation layer 1: bf16 gather, 2x unroll ----------------
__global__ __launch_bounds__(256) void agg1_kernel(
    const int* __restrict__ offsets, const int* __restrict__ csr_src,
    const float* __restrict__ el, const float* __restrict__ er,
    const float* __restrict__ mm, const float* __restrict__ den,
    const unsigned short* __restrict__ fb, const float* __restrict__ bias,
    float* __restrict__ h1) {
  __shared__ float red[3][256];
  int n = blockIdx.x;
  int t = threadIdx.x;
  int w = t >> 6, lane = t & 63;
  int h = lane >> 4;
  int off0 = offsets[n], deg = offsets[n + 1] - off0;
  float erh = er[n * 4 + h];
  float mh = mm[n * 4 + h];
  float invd = 1.0f / den[n * 4 + h];
  float4 acc = {0.f, 0.f, 0.f, 0.f};
  float4 acc2 = {0.f, 0.f, 0.f, 0.f};
  int i = w;
  for (; i + 4 < deg; i += 8) {
    int s0 = csr_src[off0 + i];
    int s1 = csr_src[off0 + i + 4];
    float e0 = el[s0 * 4 + h] + erh;
    float e1 = el[s1 * 4 + h] + erh;
    e0 = e0 > 0.f ? e0 : NEG_SLOPE * e0;
    e1 = e1 > 0.f ? e1 : NEG_SLOPE * e1;
    float a0 = __expf(e0 - mh) * invd;
    float a1 = __expf(e1 - mh) * invd;
    uint2 p0 = *(const uint2*)(fb + (size_t)s0 * 256 + lane * 4);
    uint2 p1 = *(const uint2*)(fb + (size_t)s1 * 256 + lane * 4);
    acc.x += a0 * __uint_as_float(p0.x << 16);
    acc.y += a0 * __uint_as_float(p0.x & 0xffff0000u);
    acc.z += a0 * __uint_as_float(p0.y << 16);
    acc.w += a0 * __uint_as_float(p0.y & 0xffff0000u);
    acc2.x += a1 * __uint_as_float(p1.x << 16);
    acc2.y += a1 * __uint_as_float(p1.x & 0xffff0000u);
    acc2.z += a1 * __uint_as_float(p1.y << 16);
    acc2.w += a1 * __uint_as_float(p1.y & 0xffff0000u);
  }
  if (i < deg) {
    int s0 = csr_src[off0 + i];
    float e0 = el[s0 * 4 + h] + erh;
    e0 = e0 > 0.f ? e0 : NEG_SLOPE * e0;
    float a0 = __expf(e0 - mh) * invd;
    uint2 p0 = *(const uint2*)(fb + (size_t)s0 * 256 + lane * 4);
    acc.x += a0 * __uint_as_float(p0.x << 16);
    acc.y += a0 * __uint_as_float(p0.x & 0xffff0000u);
    acc.z += a0 * __uint_as_float(p0.y << 16);
    acc.w += a0 * __uint_as_float(p0.y & 0xffff0000u);
  }
  acc.x += acc2.x;
  acc.y += acc2.y;
  acc.z += acc2.z;
  acc.w += acc2.w;
  if (w) *(float4*)(&red[w - 1][lane * 4]) = acc;
  __syncthreads();
  if (w == 0) {
    float4 r0 = *(float4*)(&red[0][lane * 4]);
    float4 r1 = *(float4*)(&red[1][lane * 4]);
    float4 r2 = *(float4*)(&red[2][lane * 4]);
    float4 b = ((const float4*)bias)[lane];
    float o[4] = {acc.x + r0.x + r1.x + r2.x + b.x,
                  acc.y + r0.y + r1.y + r2.y + b.y,
                  acc.z + r0.z + r1.z + r2.z + b.z,
                  acc.w + r0.w + r1.w + r2.w + b.w};
#pragma unroll
    for (int j = 0; j < 4; j++) o[j] = o[j] > 0.f ? o[j] : __expf(o[j]) - 1.0f;
    float4 ov = {o[0], o[1], o[2], o[3]};
    *(float4*)(h1 + (size_t)n * 256 + lane * 4) = ov;
  }
}

// ---------------- aggregation layer 2: bf16 gather ----------------
__global__ __launch_bounds__(256) void agg2_kernel(
    const int* __restrict__ offsets, const int* __restrict__ csr_src,
    const float* __restrict__ el, const float* __restrict__ er,
    const float* __restrict__ mm, const float* __restrict__ den,
    const unsigned short* __restrict__ fb2, const float* __restrict__ bias,
    float* __restrict__ out) {
  int w = threadIdx.x >> 6, lane = threadIdx.x & 63;
  int n = blockIdx.x * 4 + w;
  if (n >= N_NODES) return;
  int dg = lane & 15, eslot = lane >> 4;
  int off0 = offsets[n], deg = offsets[n + 1] - off0;
  float ern = er[n], mn = mm[n];
  float invd = 1.0f / den[n];
  float4 acc = {0.f, 0.f, 0.f, 0.f};
  for (int i = eslot; i < deg; i += 4) {
    int s = csr_src[off0 + i];
    float e = el[s] + ern;
    e = e > 0.f ? e : NEG_SLOPE * e;
    float a = __expf(e - mn) * invd;
    uint2 p = *(const uint2*)(fb2 + (size_t)s * 64 + dg * 4);
    acc.x += a * __uint_as_float(p.x << 16);
    acc.y += a * __uint_as_float(p.x & 0xffff0000u);
    acc.z += a * __uint_as_float(p.y << 16);
    acc.w += a * __uint_as_float(p.y & 0xffff0000u);
  }
#pragma unroll
  for (int off = 16; off < 64; off <<= 1) {
    acc.x += __shfl_xor(acc.x, off);
    acc.y += __shfl_xor(acc.y, off);
    acc.z += __shfl_xor(acc.z, off);
    acc.w += __shfl_xor(acc.w, off);
  }
  if (eslot == 0) {
    float4 b = ((const float4*)bias)[dg];
    float4 ov = {acc.x + b.x, acc.y + b.y, acc.z + b.z, acc.w + b.w};
    *(float4*)(out + (size_t)n * 64 + dg * 4) = ov;
  }
}

extern "C" void kernel_launch(void* const* d_in, const int* in_sizes, int n_in,
                              void* d_out, int out_size, void* d_ws,
                              size_t ws_size, hipStream_t stream) {
  const float* features = (const float*)d_in[0];
  const float* W1 = (const float*)d_in[1];
  const float* al1 = (const float*)d_in[2];
  const float* ar1 = (const float*)d_in[3];
  const float* b1 = (const float*)d_in[4];
  const float* W2 = (const float*)d_in[5];
  const float* al2 = (const float*)d_in[6];
  const float* ar2 = (const float*)d_in[7];
  const float* b2 = (const float*)d_in[8];
  const int* src = (const int*)d_in[9];
  const int* dst = (const int*)d_in[10];
  float* out = (float*)d_out;

  // Workspace (~84 MB):
  //  h1 fp32 [N,256] (agg1 out -> gemm2 A)
  //  fb bf16 [N,256] (gemm1 out) -> dead after agg1 -> fb2 bf16 [N,64] reuses
  float* h1 = (float*)d_ws;                                            // 51.2
  unsigned short* fb = (unsigned short*)(h1 + (size_t)N_NODES * 256);  // 25.6
  unsigned short* fb2 = fb;  // reuse (6.4 MB needed)
  float* el1 = (float*)(fb + (size_t)N_NODES * 256);
  float* er1 = el1 + N_NODES * 4;
  float* m1 = er1 + N_NODES * 4;
  float* d1 = m1 + N_NODES * 4;
  float* el2 = d1 + N_NODES * 4;
  float* er2 = el2 + N_NODES;
  float* m2 = er2 + N_NODES;
  float* d2 = m2 + N_NODES;
  int* counts = (int*)(d2 + N_NODES);
  int* offsets = counts + N_NODES;
  int* fill = offsets + N_NODES + 1;
  int* csr_src = fill + N_NODES;
  int* bsums = csr_src + N_EDGES;

  // W packs: b1 in d_out (dead until agg2); b2 in `fill` (dead after scatter)
  short* b1hi = (short*)d_out;
  short* b1lo = b1hi + 512 * 256;
  short* b2hi = (short*)fill;
  short* b2lo = b2hi + 256 * 64;

  // --- CSR build ---
  hipMemsetAsync(counts, 0, N_NODES * sizeof(int), stream);
  hipMemsetAsync(fill, 0, N_NODES * sizeof(int), stream);
  hist_kernel<<<(N_EDGES + 255) / 256, 256, 0, stream>>>(dst, counts);
  scan_part<<<NSCAN, 256, 0, stream>>>(counts, offsets, bsums);
  scan_top<<<1, 256, 0, stream>>>(bsums);
  scan_add<<<NSCAN, 256, 0, stream>>>(offsets, bsums);
  scatter_kernel<<<(N_EDGES + 255) / 256, 256, 0, stream>>>(src, dst, offsets,
                                                            fill, csr_src);

  // --- weight packing ---
  pack_w<<<512, 256, 0, stream>>>(W1, b1hi, b1lo, 256);
  pack_w<<<256, 64, 0, stream>>>(W2, b2hi, b2lo, 64);

  // --- layer 1 ---
  gemm_mfma<IN_DIM, 8, 4><<<1563, 256, 0, stream>>>(features, b1hi, b1lo, fb,
                                                    N_NODES);
  elr1_kernel<<<N_NODES, 256, 0, stream>>>(fb, al1, ar1, el1, er1);
  mden1_kernel<<<(N_NODES + 3) / 4, 256, 0, stream>>>(offsets, csr_src, el1,
                                                      er1, m1, d1);
  agg1_kernel<<<N_NODES, 256, 0, stream>>>(offsets, csr_src, el1, er1, m1, d1,
                                           fb, b1, h1);

  // --- layer 2 ---
  gemm_mfma<256, 2, 1><<<391, 256, 0, stream>>>(h1, b2hi, b2lo, fb2, N_NODES);
  elr2_kernel<<<(N_NODES + 3) / 4, 256, 0, stream>>>(fb2, al2, ar2, el2, er2);
  mden2_kernel<<<(N_NODES + 3) / 4, 256, 0, stream>>>(offsets, csr_src, el2,
                                                      er2, m2, d2);
  agg2_kernel<<<(N_NODES + 3) / 4, 256, 0, stream>>>(offsets, csr_src, el2, er2,
                                                     m2, d2, fb2, b2, out);
}

// Round 9
// 490.390 us; speedup vs baseline: 1.1825x; 1.1075x over previous
//
#include <hip/hip_runtime.h>

#define N_NODES 50000
#define N_EDGES 800000
#define IN_DIM 512
#define NEG_SLOPE 0.2f

typedef short short8 __attribute__((ext_vector_type(8)));
typedef float f32x16 __attribute__((ext_vector_type(16)));

// ---------------- bf16 helpers ----------------
__device__ __forceinline__ unsigned bf16rne(float f) {
  union { float f; unsigned u; } v;
  v.f = f;
  return (v.u + 0x7FFFu + ((v.u >> 16) & 1u)) >> 16;
}
__device__ __forceinline__ float bf16tof(unsigned b) {
  union { unsigned u; float f; } v;
  v.u = b << 16;
  return v.f;
}
// truncation split of A: hi = trunc16(f); lo = trunc16(f - hi). err ~2^-16.
__device__ __forceinline__ void tsplit8(float4 a, float4 b, short8& hi,
                                        short8& lo) {
  float fa[8] = {a.x, a.y, a.z, a.w, b.x, b.y, b.z, b.w};
#pragma unroll
  for (int i = 0; i < 8; i++) {
    unsigned u = __float_as_uint(fa[i]);
    hi[i] = (short)(u >> 16);
    float lof = fa[i] - __uint_as_float(u & 0xffff0000u);
    lo[i] = (short)(__float_as_uint(lof) >> 16);
  }
}

// ---------------- W pre-pack (hi plane only) into MFMA B-frag order --------
__global__ void pack_w(const float* __restrict__ W, short* __restrict__ Bhi,
                       int N) {
  int k = blockIdx.x, n = threadIdx.x;
  float w = W[(size_t)k * N + n];
  int ksub = k >> 4, kh = (k >> 3) & 1, j = k & 7;
  int nsub = n >> 5, lane2 = (n & 31) | (kh << 5);
  size_t off = (((size_t)ksub * (N >> 5) + nsub) * 64 + lane2) * 8 + j;
  Bhi[off] = (short)bf16rne(w);
}

// ---------------- split-bf16 MFMA GEMM v4 ----------------
// 32x64 wave tile; 2-term split (Ahi+Alo)x Bhi; group-2 double-buffer;
// bf16 output; fused el/er epilogue (head == ntile).
template <int K, int NSUBS, int NTILES>
__global__ __launch_bounds__(256) void gemm_mfma(
    const float* __restrict__ A, const short* __restrict__ Bhi_,
    unsigned short* __restrict__ Cb, const float* __restrict__ alv,
    const float* __restrict__ arv, float* __restrict__ el,
    float* __restrict__ er, int M) {
  const int N = NSUBS * 32;
  constexpr int U = 2;
  constexpr int G = K / 16 / U;
  int lane = threadIdx.x & 63;
  int wid = blockIdx.x * 4 + (threadIdx.x >> 6);
  int mtiles = (M + 31) >> 5;
  int mtile = wid / NTILES, ntile = wid % NTILES;
  if (mtile >= mtiles) return;
  int half = lane >> 5, l31 = lane & 31;
  int m0 = mtile * 32;
  int r0 = min(m0 + l31, M - 1);
  const float* ap = A + (size_t)r0 * K + half * 8;
  const short8* bh = (const short8*)Bhi_;
  size_t bidx = (size_t)(ntile * 2) * 64 + lane;
  f32x16 acc0 = {}, acc1 = {};
  float4 cx[U][2];
  short8 cb0[U], cb1[U];
#pragma unroll
  for (int u = 0; u < U; u++) {
    cx[u][0] = *(const float4*)(ap + u * 16);
    cx[u][1] = *(const float4*)(ap + u * 16 + 4);
    size_t bb = bidx + (size_t)u * NSUBS * 64;
    cb0[u] = bh[bb];
    cb1[u] = bh[bb + 64];
  }
  for (int g = 0; g < G; g++) {
    int gn = (g + 1 < G) ? g + 1 : g;
    float4 nx[U][2];
    short8 nb0[U], nb1[U];
#pragma unroll
    for (int u = 0; u < U; u++) {
      int ks = gn * U + u;
      nx[u][0] = *(const float4*)(ap + ks * 16);
      nx[u][1] = *(const float4*)(ap + ks * 16 + 4);
      size_t bb = bidx + (size_t)ks * NSUBS * 64;
      nb0[u] = bh[bb];
      nb1[u] = bh[bb + 64];
    }
#pragma unroll
    for (int u = 0; u < U; u++) {
      short8 ah, al8;
      tsplit8(cx[u][0], cx[u][1], ah, al8);
      acc0 = __builtin_amdgcn_mfma_f32_32x32x16_bf16(ah, cb0[u], acc0, 0, 0, 0);
      acc0 = __builtin_amdgcn_mfma_f32_32x32x16_bf16(al8, cb0[u], acc0, 0, 0, 0);
      acc1 = __builtin_amdgcn_mfma_f32_32x32x16_bf16(ah, cb1[u], acc1, 0, 0, 0);
      acc1 = __builtin_amdgcn_mfma_f32_32x32x16_bf16(al8, cb1[u], acc1, 0, 0, 0);
    }
#pragma unroll
    for (int u = 0; u < U; u++) {
      cx[u][0] = nx[u][0];
      cx[u][1] = nx[u][1];
      cb0[u] = nb0[u];
      cb1[u] = nb1[u];
    }
  }
  // C/D layout (m74/m101): col=lane&31, row=(r&3)+8*(r>>2)+4*half
  int colbase = ntile * 64 + l31;
  float wa0 = alv[colbase], wa1 = alv[colbase + 32];
  float wr0 = arv[colbase], wr1 = arv[colbase + 32];
#pragma unroll
  for (int r = 0; r < 16; r++) {
    int roff = (r & 3) + 8 * (r >> 2) + 4 * half;
    int row = m0 + roff;
    if (row < M) {
      Cb[(size_t)row * N + colbase] = (unsigned short)bf16rne(acc0[r]);
      Cb[(size_t)row * N + colbase + 32] = (unsigned short)bf16rne(acc1[r]);
    }
    float elv = acc0[r] * wa0 + acc1[r] * wa1;
    float erv = acc0[r] * wr0 + acc1[r] * wr1;
#pragma unroll
    for (int off = 1; off < 32; off <<= 1) {
      elv += __shfl_xor(elv, off);
      erv += __shfl_xor(erv, off);
    }
    if (l31 == 0 && row < M) {
      el[row * NTILES + ntile] = elv;
      er[row * NTILES + ntile] = erv;
    }
  }
}

// ---------------- CSR build ----------------
__global__ void hist_kernel(const int* __restrict__ dst,
                            int* __restrict__ counts) {
  int e = blockIdx.x * blockDim.x + threadIdx.x;
  if (e < N_EDGES) atomicAdd(&counts[dst[e]], 1);
}

#define NSCAN 196  // ceil(50000/256)
__global__ __launch_bounds__(256) void scan_part(const int* __restrict__ counts,
                                                 int* __restrict__ offsets,
                                                 int* __restrict__ bsums) {
  __shared__ int sh[256];
  int t = threadIdx.x;
  int i = blockIdx.x * 256 + t;
  int v = (i < N_NODES) ? counts[i] : 0;
  sh[t] = v;
  __syncthreads();
  for (int o = 1; o < 256; o <<= 1) {
    int x = (t >= o) ? sh[t - o] : 0;
    __syncthreads();
    sh[t] += x;
    __syncthreads();
  }
  if (i < N_NODES) offsets[i] = sh[t] - v;
  if (t == 255) bsums[blockIdx.x] = sh[255];
}
__global__ __launch_bounds__(256) void scan_top(int* __restrict__ bsums) {
  __shared__ int sh[256];
  int t = threadIdx.x;
  int v = (t < NSCAN) ? bsums[t] : 0;
  sh[t] = v;
  __syncthreads();
  for (int o = 1; o < 256; o <<= 1) {
    int x = (t >= o) ? sh[t - o] : 0;
    __syncthreads();
    sh[t] += x;
    __syncthreads();
  }
  if (t < NSCAN) bsums[t] = sh[t] - v;
}
__global__ __launch_bounds__(256) void scan_add(int* __restrict__ offsets,
                                                const int* __restrict__ bsums) {
  int i = blockIdx.x * 256 + threadIdx.x;
  if (i < N_NODES) offsets[i] += bsums[blockIdx.x];
  if (i == 0) offsets[N_NODES] = N_EDGES;
}

__global__ void scatter_kernel(const int* __restrict__ src,
                               const int* __restrict__ dst,
                               const int* __restrict__ offsets,
                               int* __restrict__ fill,
                               int* __restrict__ csr_src) {
  int e = blockIdx.x * blockDim.x + threadIdx.x;
  if (e < N_EDGES) {
    int d = dst[e];
    int pos = offsets[d] + atomicAdd(&fill[d], 1);
    csr_src[pos] = src[e];
  }
}

// ---------------- softmax max/denominator (online), separate ----------------
__global__ __launch_bounds__(256) void mden1_kernel(
    const int* __restrict__ offsets, const int* __restrict__ csr_src,
    const float* __restrict__ el, const float* __restrict__ er,
    float* __restrict__ mout, float* __restrict__ dout) {
  int w = threadIdx.x >> 6, lane = threadIdx.x & 63;
  int n = blockIdx.x * 4 + w;
  if (n >= N_NODES) return;
  int off0 = offsets[n], deg = offsets[n + 1] - off0;
  float4 erv = ((const float4*)er)[n];
  float er4[4] = {erv.x, erv.y, erv.z, erv.w};
  float m[4] = {-1e30f, -1e30f, -1e30f, -1e30f};
  float l[4] = {0.f, 0.f, 0.f, 0.f};
  for (int i = lane; i < deg; i += 64) {
    int s = csr_src[off0 + i];
    float4 elv = ((const float4*)el)[s];
    float e4[4] = {elv.x, elv.y, elv.z, elv.w};
#pragma unroll
    for (int h = 0; h < 4; h++) {
      float v = e4[h] + er4[h];
      v = v > 0.f ? v : NEG_SLOPE * v;
      float nm = fmaxf(m[h], v);
      l[h] = l[h] * __expf(m[h] - nm) + __expf(v - nm);
      m[h] = nm;
    }
  }
  for (int d = 32; d; d >>= 1) {
#pragma unroll
    for (int h = 0; h < 4; h++) {
      float mo = __shfl_down(m[h], d);
      float lo = __shfl_down(l[h], d);
      float nm = fmaxf(m[h], mo);
      l[h] = l[h] * __expf(m[h] - nm) + lo * __expf(mo - nm);
      m[h] = nm;
    }
  }
  if (lane == 0) {
#pragma unroll
    for (int h = 0; h < 4; h++) {
      mout[n * 4 + h] = m[h];
      dout[n * 4 + h] = l[h];
    }
  }
}

__global__ __launch_bounds__(256) void mden2_kernel(
    const int* __restrict__ offsets, const int* __restrict__ csr_src,
    const float* __restrict__ el, const float* __restrict__ er,
    float* __restrict__ mout, float* __restrict__ dout) {
  int w = threadIdx.x >> 6, lane = threadIdx.x & 63;
  int n = blockIdx.x * 4 + w;
  if (n >= N_NODES) return;
  int off0 = offsets[n], deg = offsets[n + 1] - off0;
  float ern = er[n];
  float m = -1e30f, l = 0.f;
  for (int i = lane; i < deg; i += 64) {
    int s = csr_src[off0 + i];
    float v = el[s] + ern;
    v = v > 0.f ? v : NEG_SLOPE * v;
    float nm = fmaxf(m, v);
    l = l * __expf(m - nm) + __expf(v - nm);
    m = nm;
  }
  for (int d = 32; d; d >>= 1) {
    float mo = __shfl_down(m, d);
    float lo = __shfl_down(l, d);
    float nm = fmaxf(m, mo);
    l = l * __expf(m - nm) + lo * __expf(mo - nm);
    m = nm;
  }
  if (lane == 0) {
    mout[n] = m;
    dout[n] = l;
  }
}

// ---------------- aggregation layer 1: bf16 gather, 2x unroll ----------------
__global__ __launch_bounds__(256) void agg1_kernel(
    const int* __restrict__ offsets, const int* __restrict__ csr_src,
    const float* __restrict__ el, const float* __restrict__ er,
    const float* __restrict__ mm, const float* __restrict__ den,
    const unsigned short* __restrict__ fb, const float* __restrict__ bias,
    float* __restrict__ h1) {
  __shared__ float red[3][256];
  int n = blockIdx.x;
  int t = threadIdx.x;
  int w = t >> 6, lane = t & 63;
  int h = lane >> 4;
  int off0 = offsets[n], deg = offsets[n + 1] - off0;
  float erh = er[n * 4 + h];
  float mh = mm[n * 4 + h];
  float invd = 1.0f / den[n * 4 + h];
  float4 acc = {0.f, 0.f, 0.f, 0.f};
  float4 acc2 = {0.f, 0.f, 0.f, 0.f};
  int i = w;
  for (; i + 4 < deg; i += 8) {
    int s0 = csr_src[off0 + i];
    int s1 = csr_src[off0 + i + 4];
    float e0 = el[s0 * 4 + h] + erh;
    float e1 = el[s1 * 4 + h] + erh;
    e0 = e0 > 0.f ? e0 : NEG_SLOPE * e0;
    e1 = e1 > 0.f ? e1 : NEG_SLOPE * e1;
    float a0 = __expf(e0 - mh) * invd;
    float a1 = __expf(e1 - mh) * invd;
    uint2 p0 = *(const uint2*)(fb + (size_t)s0 * 256 + lane * 4);
    uint2 p1 = *(const uint2*)(fb + (size_t)s1 * 256 + lane * 4);
    acc.x += a0 * __uint_as_float(p0.x << 16);
    acc.y += a0 * __uint_as_float(p0.x & 0xffff0000u);
    acc.z += a0 * __uint_as_float(p0.y << 16);
    acc.w += a0 * __uint_as_float(p0.y & 0xffff0000u);
    acc2.x += a1 * __uint_as_float(p1.x << 16);
    acc2.y += a1 * __uint_as_float(p1.x & 0xffff0000u);
    acc2.z += a1 * __uint_as_float(p1.y << 16);
    acc2.w += a1 * __uint_as_float(p1.y & 0xffff0000u);
  }
  if (i < deg) {
    int s0 = csr_src[off0 + i];
    float e0 = el[s0 * 4 + h] + erh;
    e0 = e0 > 0.f ? e0 : NEG_SLOPE * e0;
    float a0 = __expf(e0 - mh) * invd;
    uint2 p0 = *(const uint2*)(fb + (size_t)s0 * 256 + lane * 4);
    acc.x += a0 * __uint_as_float(p0.x << 16);
    acc.y += a0 * __uint_as_float(p0.x & 0xffff0000u);
    acc.z += a0 * __uint_as_float(p0.y << 16);
    acc.w += a0 * __uint_as_float(p0.y & 0xffff0000u);
  }
  acc.x += acc2.x;
  acc.y += acc2.y;
  acc.z += acc2.z;
  acc.w += acc2.w;
  if (w) *(float4*)(&red[w - 1][lane * 4]) = acc;
  __syncthreads();
  if (w == 0) {
    float4 r0 = *(float4*)(&red[0][lane * 4]);
    float4 r1 = *(float4*)(&red[1][lane * 4]);
    float4 r2 = *(float4*)(&red[2][lane * 4]);
    float4 b = ((const float4*)bias)[lane];
    float o[4] = {acc.x + r0.x + r1.x + r2.x + b.x,
                  acc.y + r0.y + r1.y + r2.y + b.y,
                  acc.z + r0.z + r1.z + r2.z + b.z,
                  acc.w + r0.w + r1.w + r2.w + b.w};
#pragma unroll
    for (int j = 0; j < 4; j++) o[j] = o[j] > 0.f ? o[j] : __expf(o[j]) - 1.0f;
    float4 ov = {o[0], o[1], o[2], o[3]};
    *(float4*)(h1 + (size_t)n * 256 + lane * 4) = ov;
  }
}

// ---------------- aggregation layer 2: bf16 gather ----------------
__global__ __launch_bounds__(256) void agg2_kernel(
    const int* __restrict__ offsets, const int* __restrict__ csr_src,
    const float* __restrict__ el, const float* __restrict__ er,
    const float* __restrict__ mm, const float* __restrict__ den,
    const unsigned short* __restrict__ fb2, const float* __restrict__ bias,
    float* __restrict__ out) {
  int w = threadIdx.x >> 6, lane = threadIdx.x & 63;
  int n = blockIdx.x * 4 + w;
  if (n >= N_NODES) return;
  int dg = lane & 15, eslot = lane >> 4;
  int off0 = offsets[n], deg = offsets[n + 1] - off0;
  float ern = er[n], mn = mm[n];
  float invd = 1.0f / den[n];
  float4 acc = {0.f, 0.f, 0.f, 0.f};
  for (int i = eslot; i < deg; i += 4) {
    int s = csr_src[off0 + i];
    float e = el[s] + ern;
    e = e > 0.f ? e : NEG_SLOPE * e;
    float a = __expf(e - mn) * invd;
    uint2 p = *(const uint2*)(fb2 + (size_t)s * 64 + dg * 4);
    acc.x += a * __uint_as_float(p.x << 16);
    acc.y += a * __uint_as_float(p.x & 0xffff0000u);
    acc.z += a * __uint_as_float(p.y << 16);
    acc.w += a * __uint_as_float(p.y & 0xffff0000u);
  }
#pragma unroll
  for (int off = 16; off < 64; off <<= 1) {
    acc.x += __shfl_xor(acc.x, off);
    acc.y += __shfl_xor(acc.y, off);
    acc.z += __shfl_xor(acc.z, off);
    acc.w += __shfl_xor(acc.w, off);
  }
  if (eslot == 0) {
    float4 b = ((const float4*)bias)[dg];
    float4 ov = {acc.x + b.x, acc.y + b.y, acc.z + b.z, acc.w + b.w};
    *(float4*)(out + (size_t)n * 64 + dg * 4) = ov;
  }
}

extern "C" void kernel_launch(void* const* d_in, const int* in_sizes, int n_in,
                              void* d_out, int out_size, void* d_ws,
                              size_t ws_size, hipStream_t stream) {
  const float* features = (const float*)d_in[0];
  const float* W1 = (const float*)d_in[1];
  const float* al1 = (const float*)d_in[2];
  const float* ar1 = (const float*)d_in[3];
  const float* b1 = (const float*)d_in[4];
  const float* W2 = (const float*)d_in[5];
  const float* al2 = (const float*)d_in[6];
  const float* ar2 = (const float*)d_in[7];
  const float* b2 = (const float*)d_in[8];
  const int* src = (const int*)d_in[9];
  const int* dst = (const int*)d_in[10];
  float* out = (float*)d_out;

  // Workspace (~84 MB):
  //  h1 fp32 [N,256] (agg1 out -> gemm2 A)
  //  fb bf16 [N,256] (gemm1 out) -> dead after agg1 -> fb2 bf16 [N,64] reuses
  float* h1 = (float*)d_ws;                                            // 51.2
  unsigned short* fb = (unsigned short*)(h1 + (size_t)N_NODES * 256);  // 25.6
  unsigned short* fb2 = fb;  // reuse (6.4 MB needed)
  float* el1 = (float*)(fb + (size_t)N_NODES * 256);
  float* er1 = el1 + N_NODES * 4;
  float* m1 = er1 + N_NODES * 4;
  float* d1 = m1 + N_NODES * 4;
  float* el2 = d1 + N_NODES * 4;
  float* er2 = el2 + N_NODES;
  float* m2 = er2 + N_NODES;
  float* d2 = m2 + N_NODES;
  int* counts = (int*)(d2 + N_NODES);
  int* offsets = counts + N_NODES;
  int* fill = offsets + N_NODES + 1;
  int* csr_src = fill + N_NODES;
  int* bsums = csr_src + N_EDGES;

  // W packs (hi plane only): b1 in d_out (dead until agg2);
  // b2 in `fill` (dead after scatter).
  short* b1hi = (short*)d_out;   // 512*256 shorts = 262 KB << 12.8 MB
  short* b2hi = (short*)fill;    // 256*64 shorts = 32 KB << 200 KB

  // --- CSR build ---
  hipMemsetAsync(counts, 0, N_NODES * sizeof(int), stream);
  hipMemsetAsync(fill, 0, N_NODES * sizeof(int), stream);
  hist_kernel<<<(N_EDGES + 255) / 256, 256, 0, stream>>>(dst, counts);
  scan_part<<<NSCAN, 256, 0, stream>>>(counts, offsets, bsums);
  scan_top<<<1, 256, 0, stream>>>(bsums);
  scan_add<<<NSCAN, 256, 0, stream>>>(offsets, bsums);
  scatter_kernel<<<(N_EDGES + 255) / 256, 256, 0, stream>>>(src, dst, offsets,
                                                            fill, csr_src);

  // --- weight packing ---
  pack_w<<<512, 256, 0, stream>>>(W1, b1hi, 256);
  pack_w<<<256, 64, 0, stream>>>(W2, b2hi, 64);

  // --- layer 1 (el/er fused into gemm epilogue) ---
  gemm_mfma<IN_DIM, 8, 4><<<1563, 256, 0, stream>>>(features, b1hi, fb, al1,
                                                    ar1, el1, er1, N_NODES);
  mden1_kernel<<<(N_NODES + 3) / 4, 256, 0, stream>>>(offsets, csr_src, el1,
                                                      er1, m1, d1);
  agg1_kernel<<<N_NODES, 256, 0, stream>>>(offsets, csr_src, el1, er1, m1, d1,
                                           fb, b1, h1);

  // --- layer 2 (el/er fused into gemm epilogue) ---
  gemm_mfma<256, 2, 1><<<391, 256, 0, stream>>>(h1, b2hi, fb2, al2, ar2, el2,
                                                er2, N_NODES);
  mden2_kernel<<<(N_NODES + 3) / 4, 256, 0, stream>>>(offsets, csr_src, el2,
                                                      er2, m2, d2);
  agg2_kernel<<<(N_NODES + 3) / 4, 256, 0, stream>>>(offsets, csr_src, el2, er2,
                                                     m2, d2, fb2, b2, out);
}